// Round 7
// baseline (23.209 us; speedup 1.0000x reference)
//
#include <hip/hip_runtime.h>
#include <math.h>

#define BATCH 128
#define GRID_N 10000
#define DIM 32
#define MCOLS 100
#define NCHUNK 8      // g-chunks in K1
#define GCHUNK 1250   // g's per chunk
#define K1BLK 256
#define K3BLK 157

// ---------------------------------------------------------------------------
// K1: partial BMU search. 32 b-groups (4 rows of x each) x 8 g-chunks (1250)
// = 256 blocks, 512 threads (2 waves/SIMD). Dot-product form matching the
// reference: d2 = max(x2 + c2 - 2*x.c, 0) with -2x pre-scaled, so the inner
// loop is 1 fma/element + shared c2 instead of sub+fma. First-index
// tie-break. Writes pmin/pidx[b*8+chunk].
// ---------------------------------------------------------------------------
__global__ __launch_bounds__(512) void k1_bmu(const float* __restrict__ x,
                                              const float* __restrict__ c,
                                              float* __restrict__ pmin,
                                              int* __restrict__ pidx) {
    const int blk   = blockIdx.x;
    const int bg    = blk >> 3;      // 0..31
    const int chunk = blk & 7;       // 0..7
    const int b0    = bg * 4;
    const int t     = threadIdx.x;

    float m2x[4][DIM];   // -2 * x row
    float x2[4];         // ||x||^2
#pragma unroll
    for (int i = 0; i < 4; ++i) {
        float s = 0.f;
#pragma unroll
        for (int d = 0; d < DIM; ++d) {
            const float v = x[(b0 + i) * DIM + d];
            s = fmaf(v, v, s);
            m2x[i][d] = -2.0f * v;
        }
        x2[i] = s;
    }

    const int gstart = chunk * GCHUNK;
    const int gend   = gstart + GCHUNK;

    float best[4] = {3.4e38f, 3.4e38f, 3.4e38f, 3.4e38f};
    int   idx[4]  = {0, 0, 0, 0};

    for (int g = gstart + t; g < gend; g += 512) {
        const float4* cr = (const float4*)(c + (size_t)g * DIM);
        float c2 = 0.f;
        float d2[4];
#pragma unroll
        for (int i = 0; i < 4; ++i) d2[i] = x2[i];
#pragma unroll
        for (int k = 0; k < 8; ++k) {
            float4 cv = cr[k];
            c2 = fmaf(cv.x, cv.x, c2);
            c2 = fmaf(cv.y, cv.y, c2);
            c2 = fmaf(cv.z, cv.z, c2);
            c2 = fmaf(cv.w, cv.w, c2);
#pragma unroll
            for (int i = 0; i < 4; ++i) {
                d2[i] = fmaf(m2x[i][4*k+0], cv.x, d2[i]);
                d2[i] = fmaf(m2x[i][4*k+1], cv.y, d2[i]);
                d2[i] = fmaf(m2x[i][4*k+2], cv.z, d2[i]);
                d2[i] = fmaf(m2x[i][4*k+3], cv.w, d2[i]);
            }
        }
#pragma unroll
        for (int i = 0; i < 4; ++i) {
            const float v = fmaxf(d2[i] + c2, 0.f);
            if (v < best[i]) { best[i] = v; idx[i] = g; }  // strict <: keeps first
        }
    }

    // 64-lane butterfly, min with smallest-index tie-break
#pragma unroll
    for (int m = 1; m < 64; m <<= 1) {
#pragma unroll
        for (int i = 0; i < 4; ++i) {
            float o  = __shfl_xor(best[i], m);
            int   oi = __shfl_xor(idx[i], m);
            if (o < best[i] || (o == best[i] && oi < idx[i])) { best[i] = o; idx[i] = oi; }
        }
    }

    __shared__ float sm[4][8];
    __shared__ int   si[4][8];
    const int wave = t >> 6;         // 0..7
    const int lane = t & 63;
    if (lane == 0) {
#pragma unroll
        for (int i = 0; i < 4; ++i) { sm[i][wave] = best[i]; si[i][wave] = idx[i]; }
    }
    __syncthreads();
    if (t < 4) {
        float bb = sm[t][0]; int bi = si[t][0];
#pragma unroll
        for (int w = 1; w < 8; ++w)
            if (sm[t][w] < bb || (sm[t][w] == bb && si[t][w] < bi)) { bb = sm[t][w]; bi = si[t][w]; }
        pmin[(b0 + t) * NCHUNK + chunk] = bb;
        pidx[(b0 + t) * NCHUNK + chunk] = bi;
    }
}

// ---------------------------------------------------------------------------
// K3: finalize argmin (redundantly per block from L2-hot 4KB partials) +
// weight update. 157 blocks x 512 threads; thread = (g_local = t&63,
// b-chunk = t>>6 of 16 rows). Two-pass LDS reduce (chunks 4..7 add into
// 0..3) keeps LDS at 34 KB. Block 0 also writes bmu_loc and mean(mindist).
// ---------------------------------------------------------------------------
__global__ __launch_bounds__(512) void k3_update(const float* __restrict__ x,
                                                 const float* __restrict__ c,
                                                 const int* __restrict__ loc,
                                                 const float* __restrict__ pmin,
                                                 const int* __restrict__ pidx,
                                                 const float* __restrict__ lrp,
                                                 float* __restrict__ out) {
    __shared__ float bi_s[BATCH], bj_s[BATCH];
    __shared__ float red[4][64][33];
    __shared__ float partial[2];

    const int t = threadIdx.x;

    // ---- finalize per-b argmin over 8 chunks ----
    float msum = 0.f;
    if (t < BATCH) {
        float best = pmin[t * NCHUNK];
        int   bi   = pidx[t * NCHUNK];
#pragma unroll
        for (int k = 1; k < NCHUNK; ++k) {
            float v = pmin[t * NCHUNK + k];
            int   i = pidx[t * NCHUNK + k];
            if (v < best || (v == best && i < bi)) { best = v; bi = i; }
        }
        const float li = (float)loc[2 * bi];
        const float lj = (float)loc[2 * bi + 1];
        bi_s[t] = li;
        bj_s[t] = lj;
        if (blockIdx.x == 0) { out[2 * t] = li; out[2 * t + 1] = lj; }
        msum = sqrtf(fmaxf(best, 0.f));
    }
#pragma unroll
    for (int m = 1; m < 64; m <<= 1) msum += __shfl_xor(msum, m);
    if (t < BATCH && (t & 63) == 0) partial[t >> 6] = msum;
    __syncthreads();
    if (blockIdx.x == 0 && t == 0) out[256] = (partial[0] + partial[1]) * (1.0f / 128.0f);

    // ---- weight update ----
    const float lr    = lrp[0];
    const float alpha = 0.05f * lr;
    const float sig   = 50.0f * lr;
    const float inv   = 1.0f / (2.0f * sig * sig + 1e-5f);

    const int gl = t & 63;           // 0..63
    const int ch = t >> 6;           // 0..7 (one wave each)
    const int g  = blockIdx.x * 64 + gl;
    const float gi = (float)(g / MCOLS);
    const float gj = (float)(g % MCOLS);

    float acc[DIM];
#pragma unroll
    for (int d = 0; d < DIM; ++d) acc[d] = 0.f;
    float s0 = 0.f;

    const int bbase = ch * 16;
    for (int i = 0; i < 16; ++i) {
        const int bu = __builtin_amdgcn_readfirstlane(bbase + i);  // wave-uniform
        const float dr = gi - bi_s[bu];
        const float dc = gj - bj_s[bu];
        const float w  = alpha * __expf(-fmaf(dr, dr, dc * dc) * inv);
        s0 += w;
        const float4* xrp = (const float4*)(x + (size_t)bu * DIM);
#pragma unroll
        for (int k = 0; k < 8; ++k) {
            float4 xv = xrp[k];
            acc[4*k+0] = fmaf(w, xv.x, acc[4*k+0]);
            acc[4*k+1] = fmaf(w, xv.y, acc[4*k+1]);
            acc[4*k+2] = fmaf(w, xv.z, acc[4*k+2]);
            acc[4*k+3] = fmaf(w, xv.w, acc[4*k+3]);
        }
    }

    // two-pass reduce: chunks 0..3 write, chunks 4..7 accumulate
    if (ch < 4) {
#pragma unroll
        for (int d = 0; d < DIM; ++d) red[ch][gl][d] = acc[d];
        red[ch][gl][32] = s0;
    }
    __syncthreads();
    if (ch >= 4) {
#pragma unroll
        for (int d = 0; d < DIM; ++d) red[ch - 4][gl][d] += acc[d];
        red[ch - 4][gl][32] += s0;
    }
    __syncthreads();

    const int gl2  = t >> 3;         // 0..63
    const int part = t & 7;          // 8 parts x 4 d's
    const int g2   = blockIdx.x * 64 + gl2;
    if (g2 < GRID_N) {
        float ssum = 0.f;
#pragma unroll
        for (int w = 0; w < 4; ++w) ssum += red[w][gl2][32];
#pragma unroll
        for (int k = 0; k < 4; ++k) {
            const int d = part * 4 + k;
            float a = 0.f;
#pragma unroll
            for (int w = 0; w < 4; ++w) a += red[w][gl2][d];
            const float cg = c[(size_t)g2 * DIM + d];
            out[257 + (size_t)g2 * DIM + d] = cg + (a - ssum * cg) * (1.0f / 128.0f);
        }
    }
}

// ---------------------------------------------------------------------------
extern "C" void kernel_launch(void* const* d_in, const int* in_sizes, int n_in,
                              void* d_out, int out_size, void* d_ws, size_t ws_size,
                              hipStream_t stream) {
    const float* x   = (const float*)d_in[0];
    const float* c   = (const float*)d_in[1];
    const int*   loc = (const int*)d_in[2];
    // d_in[3] = distance_mat: recomputed on the fly (exact for integer coords)
    const float* lrp = (const float*)d_in[4];
    float* out = (float*)d_out;

    float* pmin = (float*)d_ws;                        // 128*8 floats
    int*   pidx = (int*)((char*)d_ws + 1024 * 4);      // 128*8 ints

    hipLaunchKernelGGL(k1_bmu,    dim3(K1BLK), dim3(512), 0, stream, x, c, pmin, pidx);
    hipLaunchKernelGGL(k3_update, dim3(K3BLK), dim3(512), 0, stream, x, c, loc, pmin, pidx, lrp, out);
}

// Round 8
// 21.660 us; speedup vs baseline: 1.0715x; 1.0715x over previous
//
#include <hip/hip_runtime.h>
#include <math.h>

#define BATCH 128
#define GRID_N 10000
#define DIM 32
#define MCOLS 100
#define NCHUNK 8      // g-chunks in K1
#define GCHUNK 1250   // g's per chunk
#define K1BLK 256
#define K3BLK 157

// ---------------------------------------------------------------------------
// K1: partial BMU search. 32 b-groups (4 rows of x each) x 8 g-chunks (1250)
// = 256 blocks, 512 threads (2 waves/SIMD for L2-latency hiding).
// Direct-diff ||x-c||^2 (4 independent fma chains — measured faster than the
// dot-product form in this latency-bound regime, R7 post-mortem).
// First-index tie-break. Writes pmin/pidx[b*8+chunk].
// ---------------------------------------------------------------------------
__global__ __launch_bounds__(512) void k1_bmu(const float* __restrict__ x,
                                              const float* __restrict__ c,
                                              float* __restrict__ pmin,
                                              int* __restrict__ pidx) {
    const int blk   = blockIdx.x;
    const int bg    = blk >> 3;      // 0..31
    const int chunk = blk & 7;       // 0..7
    const int b0    = bg * 4;
    const int t     = threadIdx.x;

    float xr[4][DIM];
#pragma unroll
    for (int i = 0; i < 4; ++i)
#pragma unroll
        for (int d = 0; d < DIM; ++d)
            xr[i][d] = x[(b0 + i) * DIM + d];

    const int gstart = chunk * GCHUNK;
    const int gend   = gstart + GCHUNK;

    float best[4] = {3.4e38f, 3.4e38f, 3.4e38f, 3.4e38f};
    int   idx[4]  = {0, 0, 0, 0};

    for (int g = gstart + t; g < gend; g += 512) {
        const float4* cr = (const float4*)(c + (size_t)g * DIM);
        float d2[4] = {0.f, 0.f, 0.f, 0.f};
#pragma unroll
        for (int k = 0; k < 8; ++k) {
            float4 cv = cr[k];
#pragma unroll
            for (int i = 0; i < 4; ++i) {
                float a;
                a = xr[i][4*k+0] - cv.x; d2[i] = fmaf(a, a, d2[i]);
                a = xr[i][4*k+1] - cv.y; d2[i] = fmaf(a, a, d2[i]);
                a = xr[i][4*k+2] - cv.z; d2[i] = fmaf(a, a, d2[i]);
                a = xr[i][4*k+3] - cv.w; d2[i] = fmaf(a, a, d2[i]);
            }
        }
#pragma unroll
        for (int i = 0; i < 4; ++i)
            if (d2[i] < best[i]) { best[i] = d2[i]; idx[i] = g; }  // strict <: keeps first
    }

    // 64-lane butterfly, min with smallest-index tie-break
#pragma unroll
    for (int m = 1; m < 64; m <<= 1) {
#pragma unroll
        for (int i = 0; i < 4; ++i) {
            float o  = __shfl_xor(best[i], m);
            int   oi = __shfl_xor(idx[i], m);
            if (o < best[i] || (o == best[i] && oi < idx[i])) { best[i] = o; idx[i] = oi; }
        }
    }

    __shared__ float sm[4][8];
    __shared__ int   si[4][8];
    const int wave = t >> 6;         // 0..7
    const int lane = t & 63;
    if (lane == 0) {
#pragma unroll
        for (int i = 0; i < 4; ++i) { sm[i][wave] = best[i]; si[i][wave] = idx[i]; }
    }
    __syncthreads();
    if (t < 4) {
        float bb = sm[t][0]; int bi = si[t][0];
#pragma unroll
        for (int w = 1; w < 8; ++w)
            if (sm[t][w] < bb || (sm[t][w] == bb && si[t][w] < bi)) { bb = sm[t][w]; bi = si[t][w]; }
        pmin[(b0 + t) * NCHUNK + chunk] = bb;
        pidx[(b0 + t) * NCHUNK + chunk] = bi;
    }
}

// ---------------------------------------------------------------------------
// K3: finalize argmin (redundantly per block from L2-hot 4KB partials) +
// weight update. 157 blocks x 512 threads; thread = (g_local = t&63,
// b-chunk = t>>6 of 16 rows). Two-pass LDS reduce (chunks 4..7 add into
// 0..3) keeps LDS at 34 KB. Block 0 also writes bmu_loc and mean(mindist).
// ---------------------------------------------------------------------------
__global__ __launch_bounds__(512) void k3_update(const float* __restrict__ x,
                                                 const float* __restrict__ c,
                                                 const int* __restrict__ loc,
                                                 const float* __restrict__ pmin,
                                                 const int* __restrict__ pidx,
                                                 const float* __restrict__ lrp,
                                                 float* __restrict__ out) {
    __shared__ float bi_s[BATCH], bj_s[BATCH];
    __shared__ float red[4][64][33];
    __shared__ float partial[2];

    const int t = threadIdx.x;

    // ---- finalize per-b argmin over 8 chunks ----
    float msum = 0.f;
    if (t < BATCH) {
        float best = pmin[t * NCHUNK];
        int   bi   = pidx[t * NCHUNK];
#pragma unroll
        for (int k = 1; k < NCHUNK; ++k) {
            float v = pmin[t * NCHUNK + k];
            int   i = pidx[t * NCHUNK + k];
            if (v < best || (v == best && i < bi)) { best = v; bi = i; }
        }
        const float li = (float)loc[2 * bi];
        const float lj = (float)loc[2 * bi + 1];
        bi_s[t] = li;
        bj_s[t] = lj;
        if (blockIdx.x == 0) { out[2 * t] = li; out[2 * t + 1] = lj; }
        msum = sqrtf(fmaxf(best, 0.f));
    }
#pragma unroll
    for (int m = 1; m < 64; m <<= 1) msum += __shfl_xor(msum, m);
    if (t < BATCH && (t & 63) == 0) partial[t >> 6] = msum;
    __syncthreads();
    if (blockIdx.x == 0 && t == 0) out[256] = (partial[0] + partial[1]) * (1.0f / 128.0f);

    // ---- weight update ----
    const float lr    = lrp[0];
    const float alpha = 0.05f * lr;
    const float sig   = 50.0f * lr;
    const float inv   = 1.0f / (2.0f * sig * sig + 1e-5f);

    const int gl = t & 63;           // 0..63
    const int ch = t >> 6;           // 0..7 (one wave each)
    const int g  = blockIdx.x * 64 + gl;
    const float gi = (float)(g / MCOLS);
    const float gj = (float)(g % MCOLS);

    float acc[DIM];
#pragma unroll
    for (int d = 0; d < DIM; ++d) acc[d] = 0.f;
    float s0 = 0.f;

    const int bbase = ch * 16;
    for (int i = 0; i < 16; ++i) {
        const int bu = __builtin_amdgcn_readfirstlane(bbase + i);  // wave-uniform
        const float dr = gi - bi_s[bu];
        const float dc = gj - bj_s[bu];
        const float w  = alpha * __expf(-fmaf(dr, dr, dc * dc) * inv);
        s0 += w;
        const float4* xrp = (const float4*)(x + (size_t)bu * DIM);
#pragma unroll
        for (int k = 0; k < 8; ++k) {
            float4 xv = xrp[k];
            acc[4*k+0] = fmaf(w, xv.x, acc[4*k+0]);
            acc[4*k+1] = fmaf(w, xv.y, acc[4*k+1]);
            acc[4*k+2] = fmaf(w, xv.z, acc[4*k+2]);
            acc[4*k+3] = fmaf(w, xv.w, acc[4*k+3]);
        }
    }

    // two-pass reduce: chunks 0..3 write, chunks 4..7 accumulate
    if (ch < 4) {
#pragma unroll
        for (int d = 0; d < DIM; ++d) red[ch][gl][d] = acc[d];
        red[ch][gl][32] = s0;
    }
    __syncthreads();
    if (ch >= 4) {
#pragma unroll
        for (int d = 0; d < DIM; ++d) red[ch - 4][gl][d] += acc[d];
        red[ch - 4][gl][32] += s0;
    }
    __syncthreads();

    const int gl2  = t >> 3;         // 0..63
    const int part = t & 7;          // 8 parts x 4 d's
    const int g2   = blockIdx.x * 64 + gl2;
    if (g2 < GRID_N) {
        float ssum = 0.f;
#pragma unroll
        for (int w = 0; w < 4; ++w) ssum += red[w][gl2][32];
#pragma unroll
        for (int k = 0; k < 4; ++k) {
            const int d = part * 4 + k;
            float a = 0.f;
#pragma unroll
            for (int w = 0; w < 4; ++w) a += red[w][gl2][d];
            const float cg = c[(size_t)g2 * DIM + d];
            out[257 + (size_t)g2 * DIM + d] = cg + (a - ssum * cg) * (1.0f / 128.0f);
        }
    }
}

// ---------------------------------------------------------------------------
extern "C" void kernel_launch(void* const* d_in, const int* in_sizes, int n_in,
                              void* d_out, int out_size, void* d_ws, size_t ws_size,
                              hipStream_t stream) {
    const float* x   = (const float*)d_in[0];
    const float* c   = (const float*)d_in[1];
    const int*   loc = (const int*)d_in[2];
    // d_in[3] = distance_mat: recomputed on the fly (exact for integer coords)
    const float* lrp = (const float*)d_in[4];
    float* out = (float*)d_out;

    float* pmin = (float*)d_ws;                        // 128*8 floats
    int*   pidx = (int*)((char*)d_ws + 1024 * 4);      // 128*8 ints

    hipLaunchKernelGGL(k1_bmu,    dim3(K1BLK), dim3(512), 0, stream, x, c, pmin, pidx);
    hipLaunchKernelGGL(k3_update, dim3(K3BLK), dim3(512), 0, stream, x, c, loc, pmin, pidx, lrp, out);
}